// Round 23
// baseline (185.437 us; speedup 1.0000x reference)
//
#include <hip/hip_runtime.h>

#define BB 4096
#define TT 256
#define FF 32
#define HH 6

#define DPP_XOR1 0xB1   // quad_perm(1,0,3,2)
#define DPP_XOR2 0x4E   // quad_perm(2,3,0,1)
#define DPP_XOR3 0x1B   // quad_perm(3,2,1,0)
#define DPP_HALF 0x141  // row_half_mirror = xor 7 within 8-lane half-rows

__device__ __forceinline__ float fast_rcp(float x) { return __builtin_amdgcn_rcpf(x); }
__device__ __forceinline__ float sigmoidf(float x) { return fast_rcp(1.0f + __expf(-x)); }

template <int CTRL>
__device__ __forceinline__ float dppf(float x) {
    return __int_as_float(__builtin_amdgcn_update_dpp(
        0, __float_as_int(x), CTRL, 0xF, 0xF, true));
}
__device__ __forceinline__ float dpp_xor4(float x) {
    return dppf<DPP_HALF>(dppf<DPP_XOR3>(x));
}

typedef const __attribute__((address_space(1))) void* gas_ptr;
typedef __attribute__((address_space(3))) void* las_ptr;
__device__ __forceinline__ void gl_lds16(const float* g, float* l) {
    __builtin_amdgcn_global_load_lds((gas_ptr)g, (las_ptr)l, 16, 0, 0);
}

typedef short short8 __attribute__((ext_vector_type(8)));
typedef int i32x4 __attribute__((ext_vector_type(4)));
typedef float f32x4 __attribute__((ext_vector_type(4)));
#define MFMA16(A, B, C) __builtin_amdgcn_mfma_f32_16x16x32_bf16(A, B, C, 0, 0, 0)

__device__ __forceinline__ unsigned short rne_bf16(float f) {
    unsigned u = __float_as_uint(f);
    u = u + 0x7FFFu + ((u >> 16) & 1u);
    return (unsigned short)(u >> 16);
}
__device__ __forceinline__ float bf16f(unsigned short s) {
    return __uint_as_float(((unsigned)s) << 16);
}

// split 8 floats into hi/lo bf16 fragments using v_cvt_pk_bf16_f32 (1 instr
// per 2 elements). Rounding mode irrelevant: lo compensates hi exactly to
// bf16 precision (residual ~2^-16 relative).
__device__ __forceinline__ void cvt_split8(const float xf[8], short8& hi, short8& lo) {
    i32x4 h, l;
#pragma unroll
    for (int p = 0; p < 4; ++p) {
        int hp;
        asm("v_cvt_pk_bf16_f32 %0, %1, %2" : "=&v"(hp) : "v"(xf[2 * p]), "v"(xf[2 * p + 1]));
        const float b0 = __int_as_float(hp << 16);
        const float b1 = __int_as_float((unsigned)hp & 0xffff0000u);
        const float r0 = xf[2 * p] - b0;
        const float r1 = xf[2 * p + 1] - b1;
        int lp;
        asm("v_cvt_pk_bf16_f32 %0, %1, %2" : "=&v"(lp) : "v"(r0), "v"(r1));
        h[p] = hp; l[p] = lp;
    }
    hi = *(short8*)&h;
    lo = *(short8*)&l;
}

// K1 v7 (MFMA, verified numerics): 2 independent 16-item tiles interleaved,
// v_cvt_pk_bf16_f32 for all input splits, launch_bounds(256,6) (VGPR cap 85,
// 6 blocks/CU), DITERS=2 (grid 4096) for tail amortization.
#define K1_DITERS 2
__global__ __launch_bounds__(256, 6) void k_attn_xz(
    const float* __restrict__ x, const float* __restrict__ Wa, const float* __restrict__ ba,
    const float* __restrict__ Wl, const float* __restrict__ bl, float* __restrict__ xz)
{
    const int lane = threadIdx.x & 63;
    const int wid = threadIdx.x >> 6;
    const int l15 = lane & 15;
    const int g = lane >> 4;

    __shared__ __align__(16) float ebuf[4][2 * 16 * 36];   // per-wave A/B staging
    float* myA = ebuf[wid];
    float* myB = ebuf[wid] + 16 * 36;

    // persistent B-frags: Wa tiles (cols 0-15, 16-31), Wl tiles (cols 0-15, 16-23+pad)
    short8 waH0, waL0, waH1, waL1, wlH0, wlL0, wlH1, wlL1;
#pragma unroll
    for (int e = 0; e < 8; ++e) {
        const int k = 4 * g + (e & 3) + 16 * (e >> 2);
        {
            const float w0 = Wa[k * 32 + l15];
            const unsigned short h0 = rne_bf16(w0);
            waH0[e] = (short)h0; waL0[e] = (short)rne_bf16(w0 - bf16f(h0));
            const float w1 = Wa[k * 32 + 16 + l15];
            const unsigned short h1 = rne_bf16(w1);
            waH1[e] = (short)h1; waL1[e] = (short)rne_bf16(w1 - bf16f(h1));
        }
        {
            const float v0 = Wl[k * 24 + l15];
            const unsigned short h0 = rne_bf16(v0);
            wlH0[e] = (short)h0; wlL0[e] = (short)rne_bf16(v0 - bf16f(h0));
            const float v1 = (l15 < 8) ? Wl[k * 24 + 16 + l15] : 0.0f;
            const unsigned short h1 = rne_bf16(v1);
            wlH1[e] = (short)h1; wlL1[e] = (short)rne_bf16(v1 - bf16f(h1));
        }
    }
    const float ba0 = ba[l15];
    const float ba1 = ba[16 + l15];
    const int c1 = 16 + l15;
    const float bl0 = bl[l15];
    const float bl1 = (l15 < 8) ? bl[c1] : 0.0f;
    const int off0 = (l15 % 6) * 4 + l15 / 6;
    const int off1 = (c1 % 6) * 4 + c1 / 6;

    const int gw = blockIdx.x * 4 + wid;

    for (int it = 0; it < K1_DITERS; ++it) {
        const int ibaseA = (gw * (2 * K1_DITERS) + 2 * it) * 16;
        const int ibaseB = ibaseA + 16;

        // ---- load x rows (A layout) for both tiles
        const float* xrA = x + (size_t)(ibaseA + l15) * FF + 4 * g;
        const float* xrB = x + (size_t)(ibaseB + l15) * FF + 4 * g;
        const float4 xa0 = *(const float4*)(xrA);
        const float4 xa1 = *(const float4*)(xrA + 16);
        const float4 xb0 = *(const float4*)(xrB);
        const float4 xb1 = *(const float4*)(xrB + 16);
        float xaA[8] = {xa0.x, xa0.y, xa0.z, xa0.w, xa1.x, xa1.y, xa1.z, xa1.w};
        float xaB[8] = {xb0.x, xb0.y, xb0.z, xb0.w, xb1.x, xb1.y, xb1.z, xb1.w};
        short8 ahA, alA, ahB, alB;
        cvt_split8(xaA, ahA, alA);
        cvt_split8(xaB, ahB, alB);

        // ---- scores (3-term split), both tiles interleaved
        f32x4 sA0 = {0.f,0.f,0.f,0.f}, sA1 = {0.f,0.f,0.f,0.f};
        f32x4 sB0 = {0.f,0.f,0.f,0.f}, sB1 = {0.f,0.f,0.f,0.f};
        sA0 = MFMA16(alA, waH0, sA0); sB0 = MFMA16(alB, waH0, sB0);
        sA0 = MFMA16(ahA, waL0, sA0); sB0 = MFMA16(ahB, waL0, sB0);
        sA0 = MFMA16(ahA, waH0, sA0); sB0 = MFMA16(ahB, waH0, sB0);
        sA1 = MFMA16(alA, waH1, sA1); sB1 = MFMA16(alB, waH1, sB1);
        sA1 = MFMA16(ahA, waL1, sA1); sB1 = MFMA16(ahB, waL1, sB1);
        sA1 = MFMA16(ahA, waH1, sA1); sB1 = MFMA16(ahB, waH1, sB1);

        // ---- exp + row-sum (16-lane xor reduce), both tiles
        float e0A[4], e1A[4], rsA[4], e0B[4], e1B[4], rsB[4];
#pragma unroll
        for (int r = 0; r < 4; ++r) {
            e0A[r] = __expf(sA0[r] + ba0);
            e1A[r] = __expf(sA1[r] + ba1);
            e0B[r] = __expf(sB0[r] + ba0);
            e1B[r] = __expf(sB1[r] + ba1);
            float tA = e0A[r] + e1A[r];
            float tB = e0B[r] + e1B[r];
            tA += __shfl_xor(tA, 1); tB += __shfl_xor(tB, 1);
            tA += __shfl_xor(tA, 2); tB += __shfl_xor(tB, 2);
            tA += __shfl_xor(tA, 4); tB += __shfl_xor(tB, 4);
            tA += __shfl_xor(tA, 8); tB += __shfl_xor(tB, 8);
            rsA[r] = fast_rcp(tA);
            rsB[r] = fast_rcp(tB);
        }

        // ---- e: C layout -> LDS (stride 36) -> A layout, both tiles
#pragma unroll
        for (int r = 0; r < 4; ++r) {
            myA[(4 * g + r) * 36 + l15] = e0A[r];
            myA[(4 * g + r) * 36 + 16 + l15] = e1A[r];
            myB[(4 * g + r) * 36 + l15] = e0B[r];
            myB[(4 * g + r) * 36 + 16 + l15] = e1B[r];
        }
        const float* erA = myA + l15 * 36 + 4 * g;
        const float* erB = myB + l15 * 36 + 4 * g;
        const float4 ecA0 = *(const float4*)(erA);
        const float4 ecA1 = *(const float4*)(erA + 16);
        const float4 ecB0 = *(const float4*)(erB);
        const float4 ecB1 = *(const float4*)(erB + 16);

        float pA[8] = {xaA[0] * ecA0.x, xaA[1] * ecA0.y, xaA[2] * ecA0.z, xaA[3] * ecA0.w,
                       xaA[4] * ecA1.x, xaA[5] * ecA1.y, xaA[6] * ecA1.z, xaA[7] * ecA1.w};
        float pB[8] = {xaB[0] * ecB0.x, xaB[1] * ecB0.y, xaB[2] * ecB0.z, xaB[3] * ecB0.w,
                       xaB[4] * ecB1.x, xaB[5] * ecB1.y, xaB[6] * ecB1.z, xaB[7] * ecB1.w};
        short8 phA, plA, phB, plB;
        cvt_split8(pA, phA, plA);
        cvt_split8(pB, phB, plB);

        // ---- z GEMM, both tiles interleaved
        f32x4 zA0 = {0.f,0.f,0.f,0.f}, zA1 = {0.f,0.f,0.f,0.f};
        f32x4 zB0 = {0.f,0.f,0.f,0.f}, zB1 = {0.f,0.f,0.f,0.f};
        zA0 = MFMA16(plA, wlH0, zA0); zB0 = MFMA16(plB, wlH0, zB0);
        zA0 = MFMA16(phA, wlL0, zA0); zB0 = MFMA16(phB, wlL0, zB0);
        zA0 = MFMA16(phA, wlH0, zA0); zB0 = MFMA16(phB, wlH0, zB0);
        zA1 = MFMA16(plA, wlH1, zA1); zB1 = MFMA16(plB, wlH1, zB1);
        zA1 = MFMA16(phA, wlL1, zA1); zB1 = MFMA16(phB, wlL1, zB1);
        zA1 = MFMA16(phA, wlH1, zA1); zB1 = MFMA16(phB, wlH1, zB1);

        // ---- scale, +bl, scatter to LDS compact, coalesced store, both tiles
#pragma unroll
        for (int r = 0; r < 4; ++r) {
            myA[(4 * g + r) * 24 + off0] = fmaf(zA0[r], rsA[r], bl0);
            myB[(4 * g + r) * 24 + off0] = fmaf(zB0[r], rsB[r], bl0);
            if (l15 < 8) {
                myA[(4 * g + r) * 24 + off1] = fmaf(zA1[r], rsA[r], bl1);
                myB[(4 * g + r) * 24 + off1] = fmaf(zB1[r], rsB[r], bl1);
            }
        }
        float* opA = xz + (size_t)ibaseA * 24 + lane * 6;
        float* opB = xz + (size_t)ibaseB * 24 + lane * 6;
        const float* zrA = myA + lane * 6;
        const float* zrB = myB + lane * 6;
        const float2 a0 = *(const float2*)(zrA);
        const float2 a1 = *(const float2*)(zrA + 2);
        const float2 a2 = *(const float2*)(zrA + 4);
        const float2 b0 = *(const float2*)(zrB);
        const float2 b1 = *(const float2*)(zrB + 2);
        const float2 b2 = *(const float2*)(zrB + 4);
        *(float2*)(opA) = a0;
        *(float2*)(opA + 2) = a1;
        *(float2*)(opA + 4) = a2;
        *(float2*)(opB) = b0;
        *(float2*)(opB + 2) = b1;
        *(float2*)(opB + 4) = b2;
    }
}

// One LSTM step (defer-max c-softmax, verified). Returns hn.
__device__ __forceinline__ float chain_step(
    float hl[8], float& c, float& r2,
    const float Ui[8], const float Uf[8], const float Ug[8], const float Uo[8],
    const float4 z4, const bool real)
{
    float di0 = hl[0]*Ui[0], di1 = hl[4]*Ui[4];
    float df0 = hl[0]*Uf[0], df1 = hl[4]*Uf[4];
    float dg0 = hl[0]*Ug[0], dg1 = hl[4]*Ug[4];
    float dq0 = hl[0]*Uo[0], dq1 = hl[4]*Uo[4];
#pragma unroll
    for (int m = 1; m < 4; ++m) {
        di0 = fmaf(hl[m], Ui[m], di0); di1 = fmaf(hl[m+4], Ui[m+4], di1);
        df0 = fmaf(hl[m], Uf[m], df0); df1 = fmaf(hl[m+4], Uf[m+4], df1);
        dg0 = fmaf(hl[m], Ug[m], dg0); dg1 = fmaf(hl[m+4], Ug[m+4], dg1);
        dq0 = fmaf(hl[m], Uo[m], dq0); dq1 = fmaf(hl[m+4], Uo[m+4], dq1);
    }
    const float zi = fmaf(di0 + di1, r2, z4.x);
    const float zf = fmaf(df0 + df1, r2, z4.y);
    const float zg = fmaf(dg0 + dg1, r2, z4.z);
    const float zo = fmaf(dq0 + dq1, r2, z4.w);

    const float iv = sigmoidf(zi);
    const float fv = sigmoidf(zf);
    const float ov = sigmoidf(zo);

    const float eg = real ? __expf(zg) : 0.0f;
    float s1 = eg;
    s1 += dppf<DPP_XOR1>(s1);
    s1 += dppf<DPP_XOR2>(s1);
    s1 += dpp_xor4(s1);
    c = fmaf(fv, c, (iv * eg) * fast_rcp(s1));

    const float ec = real ? __expf(c) : 0.0f;   // defer-max (uniform exp(-m) cancels)
    float s2 = ec;
    s2 += dppf<DPP_XOR1>(s2);
    s2 += dppf<DPP_XOR2>(s2);
    s2 += dpp_xor4(s2);

    const float ovec = ov * ec;
    hl[0] = ovec;
    hl[1] = dppf<DPP_XOR1>(ovec);
    hl[2] = dppf<DPP_XOR2>(ovec);
    hl[3] = dppf<DPP_XOR3>(ovec);
    const float h7 = dppf<DPP_HALF>(ovec);
    hl[7] = h7;
    hl[6] = dppf<DPP_XOR1>(h7);
    hl[5] = dppf<DPP_XOR2>(h7);
    hl[4] = dppf<DPP_XOR3>(h7);
    r2 = fast_rcp(s2);
    return ovec * r2;
}

// K2 (byte-identical to R17-R22, verified): deferred-y scan + parallel dense(10).
__global__ __launch_bounds__(64, 1) void k_scan(
    const float* __restrict__ xz, const float* __restrict__ Ul,
    const float* __restrict__ W10, const float* __restrict__ b10,
    const float* __restrict__ Wo, const float* __restrict__ bo,
    float* __restrict__ out)
{
    const int lane = threadIdx.x;
    const int j = lane & 7;
    const int grp = lane >> 3;
    const int b = blockIdx.x * 8 + grp;
    const bool real = (j < HH);

    __shared__ __align__(1024) float ring[16 * 256];   // 16 steps x 1KB
    __shared__ __align__(16) float h_lds[TT * 64];     // 64KB: h[t][lane]

    float Ui[8], Uf[8], Ug[8], Uo[8];
#pragma unroll
    for (int m = 0; m < 8; ++m) {
        const int src = j ^ m;
        const bool ok = real && (src < HH);
        const float* row = Ul + (ok ? src : 0) * 24;
        Ui[m] = ok ? row[0  + j] : 0.0f;
        Uf[m] = ok ? row[6  + j] : 0.0f;
        Ug[m] = ok ? row[12 + j] : 0.0f;
        Uo[m] = ok ? row[18 + j] : 0.0f;
    }

    float hl[8];
    float r2 = 1.0f, c = 0.0f;
#pragma unroll
    for (int m = 0; m < 8; ++m) hl[m] = 0.0f;

    const float* gsrc = xz + (size_t)b * (TT * 24) + j * 4;

#define STAGE(G) { \
        const float* s_ = gsrc + (size_t)((G) * 8) * 24; \
        float* lb_ = ring + (((G) * 8) & 15) * 256; \
        _Pragma("unroll") \
        for (int k_ = 0; k_ < 8; ++k_) gl_lds16(s_ + k_ * 24, lb_ + k_ * 256); }

    STAGE(0) STAGE(1)
    asm volatile("s_waitcnt vmcnt(8)" ::: "memory");   // group 0 resident

    float4 zcur = *(const float4*)(ring + 0 * 256 + lane * 4);
    float4 zn1  = *(const float4*)(ring + 1 * 256 + lane * 4);

#define STEP(K) { \
        const float4 zn2 = *(const float4*)(ring + (((sb + (K) + 2) & 15) << 8) + lane * 4); \
        const float hn = chain_step(hl, c, r2, Ui, Uf, Ug, Uo, zcur, real); \
        h_lds[((t0 + (K)) << 6) + lane] = hn; \
        zcur = zn1; zn1 = zn2; }

#pragma unroll 1
    for (int gi = 0; gi < 32; ++gi) {
        const int t0 = gi * 8;
        const int sb = (gi & 1) * 8;
        STEP(0) STEP(1) STEP(2) STEP(3) STEP(4) STEP(5)
        if (gi < 30) {
            STAGE(gi + 2)
            asm volatile("s_waitcnt vmcnt(8)" ::: "memory");
        } else if (gi == 30) {
            asm volatile("s_waitcnt vmcnt(0)" ::: "memory");   // group 31 resident
        }
        STEP(6) STEP(7)
    }
#undef STEP
#undef STAGE

    asm volatile("s_waitcnt lgkmcnt(0)" ::: "memory");
    __builtin_amdgcn_sched_barrier(0);

    // Phase 2: y[p] = sum over my t-slice {t = 8*tb + j} of sum_u h[t][u]*W10[t*6+u][p]
    float yl[10];
#pragma unroll
    for (int p = 0; p < 10; ++p) yl[p] = 0.0f;

#pragma unroll 2
    for (int tb = 0; tb < 32; ++tb) {
        const int t = tb * 8 + j;
        const float* hb = h_lds + (t << 6) + (grp << 3);
        const float2 h01 = *(const float2*)(hb + 0);
        const float2 h23 = *(const float2*)(hb + 2);
        const float2 h45 = *(const float2*)(hb + 4);
        const float* wr = W10 + (size_t)t * 60;
#define ACCU(U, HV) { \
        const float2 w0 = *(const float2*)(wr + (U) * 10 + 0); \
        const float2 w1 = *(const float2*)(wr + (U) * 10 + 2); \
        const float2 w2 = *(const float2*)(wr + (U) * 10 + 4); \
        const float2 w3 = *(const float2*)(wr + (U) * 10 + 6); \
        const float2 w4 = *(const float2*)(wr + (U) * 10 + 8); \
        yl[0] = fmaf(HV, w0.x, yl[0]); yl[1] = fmaf(HV, w0.y, yl[1]); \
        yl[2] = fmaf(HV, w1.x, yl[2]); yl[3] = fmaf(HV, w1.y, yl[3]); \
        yl[4] = fmaf(HV, w2.x, yl[4]); yl[5] = fmaf(HV, w2.y, yl[5]); \
        yl[6] = fmaf(HV, w3.x, yl[6]); yl[7] = fmaf(HV, w3.y, yl[7]); \
        yl[8] = fmaf(HV, w4.x, yl[8]); yl[9] = fmaf(HV, w4.y, yl[9]); }
        ACCU(0, h01.x) ACCU(1, h01.y) ACCU(2, h23.x)
        ACCU(3, h23.y) ACCU(4, h45.x) ACCU(5, h45.y)
#undef ACCU
    }

#pragma unroll
    for (int p = 0; p < 10; ++p) {
        float v = yl[p];
        v += dppf<DPP_XOR1>(v);
        v += dppf<DPP_XOR2>(v);
        v += dpp_xor4(v);
        yl[p] = v;
    }

    float o8 = bo[j];
#pragma unroll
    for (int p = 0; p < 10; ++p) o8 = fmaf(yl[p] + b10[p], Wo[p * 8 + j], o8);
    out[(size_t)b * 8 + j] = o8;
}

extern "C" void kernel_launch(void* const* d_in, const int* in_sizes, int n_in,
                              void* d_out, int out_size, void* d_ws, size_t ws_size,
                              hipStream_t stream) {
    const float* x   = (const float*)d_in[0];
    const float* Wa  = (const float*)d_in[1];
    const float* ba  = (const float*)d_in[2];
    const float* Wl  = (const float*)d_in[3];
    const float* Ul  = (const float*)d_in[4];
    const float* bl  = (const float*)d_in[5];
    const float* W10 = (const float*)d_in[6];
    const float* b10 = (const float*)d_in[7];
    const float* Wo  = (const float*)d_in[8];
    const float* bo  = (const float*)d_in[9];
    float* out = (float*)d_out;
    float* xz  = (float*)d_ws;   // BB*TT*24*4 = 96 MiB

    // per block: 4 waves x 2 tiles x K1_DITERS x 16 = 256 items -> 4096 blocks
    hipLaunchKernelGGL(k_attn_xz, dim3(BB * TT / (16 * 2 * K1_DITERS * 4)), dim3(256), 0, stream,
                       x, Wa, ba, Wl, bl, xz);
    hipLaunchKernelGGL(k_scan, dim3(BB / 8), dim3(64), 0, stream,
                       xz, Ul, W10, b10, Wo, bo, out);
}

// Round 24
// 104.563 us; speedup vs baseline: 1.7734x; 1.7734x over previous
//
#include <hip/hip_runtime.h>

#define BB 4096
#define TT 256
#define FF 32
#define HH 6

#define DPP_XOR1 0xB1   // quad_perm(1,0,3,2)
#define DPP_XOR2 0x4E   // quad_perm(2,3,0,1)
#define DPP_XOR3 0x1B   // quad_perm(3,2,1,0)
#define DPP_HALF 0x141  // row_half_mirror = xor 7 within 8-lane half-rows

__device__ __forceinline__ float fast_rcp(float x) { return __builtin_amdgcn_rcpf(x); }
__device__ __forceinline__ float sigmoidf(float x) { return fast_rcp(1.0f + __expf(-x)); }

template <int CTRL>
__device__ __forceinline__ float dppf(float x) {
    return __int_as_float(__builtin_amdgcn_update_dpp(
        0, __float_as_int(x), CTRL, 0xF, 0xF, true));
}
__device__ __forceinline__ float dpp_xor4(float x) {
    return dppf<DPP_HALF>(dppf<DPP_XOR3>(x));
}

typedef const __attribute__((address_space(1))) void* gas_ptr;
typedef __attribute__((address_space(3))) void* las_ptr;
__device__ __forceinline__ void gl_lds16(const float* g, float* l) {
    __builtin_amdgcn_global_load_lds((gas_ptr)g, (las_ptr)l, 16, 0, 0);
}

typedef short short8 __attribute__((ext_vector_type(8)));
typedef int i32x4 __attribute__((ext_vector_type(4)));
typedef float f32x4 __attribute__((ext_vector_type(4)));
#define MFMA16(A, B, C) __builtin_amdgcn_mfma_f32_16x16x32_bf16(A, B, C, 0, 0, 0)

__device__ __forceinline__ unsigned short rne_bf16(float f) {
    unsigned u = __float_as_uint(f);
    u = u + 0x7FFFu + ((u >> 16) & 1u);
    return (unsigned short)(u >> 16);
}
__device__ __forceinline__ float bf16f(unsigned short s) {
    return __uint_as_float(((unsigned)s) << 16);
}

// split 8 floats into hi/lo bf16 fragments via v_cvt_pk_bf16_f32 (1 instr per
// 2 elems). lo compensates hi exactly to bf16 precision; rounding mode of the
// pack is irrelevant to the 3-term MFMA sum's accuracy.
__device__ __forceinline__ void cvt_split8(const float xf[8], short8& hi, short8& lo) {
    i32x4 h, l;
#pragma unroll
    for (int p = 0; p < 4; ++p) {
        int hp;
        asm("v_cvt_pk_bf16_f32 %0, %1, %2" : "=&v"(hp) : "v"(xf[2 * p]), "v"(xf[2 * p + 1]));
        const float b0 = __int_as_float(hp << 16);
        const float b1 = __int_as_float((unsigned)hp & 0xffff0000u);
        const float r0 = xf[2 * p] - b0;
        const float r1 = xf[2 * p + 1] - b1;
        int lp;
        asm("v_cvt_pk_bf16_f32 %0, %1, %2" : "=&v"(lp) : "v"(r0), "v"(r1));
        h[p] = hp; l[p] = lp;
    }
    hi = *(short8*)&h;
    lo = *(short8*)&l;
}

// K1 v8: EXACT R22 structure ((256,4), DITERS=4, 2-tile interleave — the
// best-measured no-spill config) with the single delta of cvt_pk splits.
#define K1_DITERS 4
__global__ __launch_bounds__(256, 4) void k_attn_xz(
    const float* __restrict__ x, const float* __restrict__ Wa, const float* __restrict__ ba,
    const float* __restrict__ Wl, const float* __restrict__ bl, float* __restrict__ xz)
{
    const int lane = threadIdx.x & 63;
    const int wid = threadIdx.x >> 6;
    const int l15 = lane & 15;
    const int g = lane >> 4;

    __shared__ __align__(16) float ebuf[4][2 * 16 * 36];   // per-wave A/B staging
    float* myA = ebuf[wid];
    float* myB = ebuf[wid] + 16 * 36;

    short8 waH0, waL0, waH1, waL1, wlH0, wlL0, wlH1, wlL1;
#pragma unroll
    for (int e = 0; e < 8; ++e) {
        const int k = 4 * g + (e & 3) + 16 * (e >> 2);
        {
            const float w0 = Wa[k * 32 + l15];
            const unsigned short h0 = rne_bf16(w0);
            waH0[e] = (short)h0; waL0[e] = (short)rne_bf16(w0 - bf16f(h0));
            const float w1 = Wa[k * 32 + 16 + l15];
            const unsigned short h1 = rne_bf16(w1);
            waH1[e] = (short)h1; waL1[e] = (short)rne_bf16(w1 - bf16f(h1));
        }
        {
            const float v0 = Wl[k * 24 + l15];
            const unsigned short h0 = rne_bf16(v0);
            wlH0[e] = (short)h0; wlL0[e] = (short)rne_bf16(v0 - bf16f(h0));
            const float v1 = (l15 < 8) ? Wl[k * 24 + 16 + l15] : 0.0f;
            const unsigned short h1 = rne_bf16(v1);
            wlH1[e] = (short)h1; wlL1[e] = (short)rne_bf16(v1 - bf16f(h1));
        }
    }
    const float ba0 = ba[l15];
    const float ba1 = ba[16 + l15];
    const int c1 = 16 + l15;
    const float bl0 = bl[l15];
    const float bl1 = (l15 < 8) ? bl[c1] : 0.0f;
    const int off0 = (l15 % 6) * 4 + l15 / 6;
    const int off1 = (c1 % 6) * 4 + c1 / 6;

    const int gw = blockIdx.x * 4 + wid;

    for (int it = 0; it < K1_DITERS; ++it) {
        const int ibaseA = (gw * (2 * K1_DITERS) + 2 * it) * 16;
        const int ibaseB = ibaseA + 16;

        const float* xrA = x + (size_t)(ibaseA + l15) * FF + 4 * g;
        const float* xrB = x + (size_t)(ibaseB + l15) * FF + 4 * g;
        const float4 xa0 = *(const float4*)(xrA);
        const float4 xa1 = *(const float4*)(xrA + 16);
        const float4 xb0 = *(const float4*)(xrB);
        const float4 xb1 = *(const float4*)(xrB + 16);
        float xaA[8] = {xa0.x, xa0.y, xa0.z, xa0.w, xa1.x, xa1.y, xa1.z, xa1.w};
        float xaB[8] = {xb0.x, xb0.y, xb0.z, xb0.w, xb1.x, xb1.y, xb1.z, xb1.w};
        short8 ahA, alA, ahB, alB;
        cvt_split8(xaA, ahA, alA);
        cvt_split8(xaB, ahB, alB);

        f32x4 sA0 = {0.f,0.f,0.f,0.f}, sA1 = {0.f,0.f,0.f,0.f};
        f32x4 sB0 = {0.f,0.f,0.f,0.f}, sB1 = {0.f,0.f,0.f,0.f};
        sA0 = MFMA16(alA, waH0, sA0); sB0 = MFMA16(alB, waH0, sB0);
        sA0 = MFMA16(ahA, waL0, sA0); sB0 = MFMA16(ahB, waL0, sB0);
        sA0 = MFMA16(ahA, waH0, sA0); sB0 = MFMA16(ahB, waH0, sB0);
        sA1 = MFMA16(alA, waH1, sA1); sB1 = MFMA16(alB, waH1, sB1);
        sA1 = MFMA16(ahA, waL1, sA1); sB1 = MFMA16(ahB, waL1, sB1);
        sA1 = MFMA16(ahA, waH1, sA1); sB1 = MFMA16(ahB, waH1, sB1);

        float e0A[4], e1A[4], rsA[4], e0B[4], e1B[4], rsB[4];
#pragma unroll
        for (int r = 0; r < 4; ++r) {
            e0A[r] = __expf(sA0[r] + ba0);
            e1A[r] = __expf(sA1[r] + ba1);
            e0B[r] = __expf(sB0[r] + ba0);
            e1B[r] = __expf(sB1[r] + ba1);
            float tA = e0A[r] + e1A[r];
            float tB = e0B[r] + e1B[r];
            tA += __shfl_xor(tA, 1); tB += __shfl_xor(tB, 1);
            tA += __shfl_xor(tA, 2); tB += __shfl_xor(tB, 2);
            tA += __shfl_xor(tA, 4); tB += __shfl_xor(tB, 4);
            tA += __shfl_xor(tA, 8); tB += __shfl_xor(tB, 8);
            rsA[r] = fast_rcp(tA);
            rsB[r] = fast_rcp(tB);
        }

#pragma unroll
        for (int r = 0; r < 4; ++r) {
            myA[(4 * g + r) * 36 + l15] = e0A[r];
            myA[(4 * g + r) * 36 + 16 + l15] = e1A[r];
            myB[(4 * g + r) * 36 + l15] = e0B[r];
            myB[(4 * g + r) * 36 + 16 + l15] = e1B[r];
        }
        const float* erA = myA + l15 * 36 + 4 * g;
        const float* erB = myB + l15 * 36 + 4 * g;
        const float4 ecA0 = *(const float4*)(erA);
        const float4 ecA1 = *(const float4*)(erA + 16);
        const float4 ecB0 = *(const float4*)(erB);
        const float4 ecB1 = *(const float4*)(erB + 16);

        float pA[8] = {xaA[0] * ecA0.x, xaA[1] * ecA0.y, xaA[2] * ecA0.z, xaA[3] * ecA0.w,
                       xaA[4] * ecA1.x, xaA[5] * ecA1.y, xaA[6] * ecA1.z, xaA[7] * ecA1.w};
        float pB[8] = {xaB[0] * ecB0.x, xaB[1] * ecB0.y, xaB[2] * ecB0.z, xaB[3] * ecB0.w,
                       xaB[4] * ecB1.x, xaB[5] * ecB1.y, xaB[6] * ecB1.z, xaB[7] * ecB1.w};
        short8 phA, plA, phB, plB;
        cvt_split8(pA, phA, plA);
        cvt_split8(pB, phB, plB);

        f32x4 zA0 = {0.f,0.f,0.f,0.f}, zA1 = {0.f,0.f,0.f,0.f};
        f32x4 zB0 = {0.f,0.f,0.f,0.f}, zB1 = {0.f,0.f,0.f,0.f};
        zA0 = MFMA16(plA, wlH0, zA0); zB0 = MFMA16(plB, wlH0, zB0);
        zA0 = MFMA16(phA, wlL0, zA0); zB0 = MFMA16(phB, wlL0, zB0);
        zA0 = MFMA16(phA, wlH0, zA0); zB0 = MFMA16(phB, wlH0, zB0);
        zA1 = MFMA16(plA, wlH1, zA1); zB1 = MFMA16(plB, wlH1, zB1);
        zA1 = MFMA16(phA, wlL1, zA1); zB1 = MFMA16(phB, wlL1, zB1);
        zA1 = MFMA16(phA, wlH1, zA1); zB1 = MFMA16(phB, wlH1, zB1);

#pragma unroll
        for (int r = 0; r < 4; ++r) {
            myA[(4 * g + r) * 24 + off0] = fmaf(zA0[r], rsA[r], bl0);
            myB[(4 * g + r) * 24 + off0] = fmaf(zB0[r], rsB[r], bl0);
            if (l15 < 8) {
                myA[(4 * g + r) * 24 + off1] = fmaf(zA1[r], rsA[r], bl1);
                myB[(4 * g + r) * 24 + off1] = fmaf(zB1[r], rsB[r], bl1);
            }
        }
        float* opA = xz + (size_t)ibaseA * 24 + lane * 6;
        float* opB = xz + (size_t)ibaseB * 24 + lane * 6;
        const float* zrA = myA + lane * 6;
        const float* zrB = myB + lane * 6;
        const float2 a0 = *(const float2*)(zrA);
        const float2 a1 = *(const float2*)(zrA + 2);
        const float2 a2 = *(const float2*)(zrA + 4);
        const float2 b0 = *(const float2*)(zrB);
        const float2 b1 = *(const float2*)(zrB + 2);
        const float2 b2 = *(const float2*)(zrB + 4);
        *(float2*)(opA) = a0;
        *(float2*)(opA + 2) = a1;
        *(float2*)(opA + 4) = a2;
        *(float2*)(opB) = b0;
        *(float2*)(opB + 2) = b1;
        *(float2*)(opB + 4) = b2;
    }
}

// One LSTM step (defer-max c-softmax, verified). Returns hn.
__device__ __forceinline__ float chain_step(
    float hl[8], float& c, float& r2,
    const float Ui[8], const float Uf[8], const float Ug[8], const float Uo[8],
    const float4 z4, const bool real)
{
    float di0 = hl[0]*Ui[0], di1 = hl[4]*Ui[4];
    float df0 = hl[0]*Uf[0], df1 = hl[4]*Uf[4];
    float dg0 = hl[0]*Ug[0], dg1 = hl[4]*Ug[4];
    float dq0 = hl[0]*Uo[0], dq1 = hl[4]*Uo[4];
#pragma unroll
    for (int m = 1; m < 4; ++m) {
        di0 = fmaf(hl[m], Ui[m], di0); di1 = fmaf(hl[m+4], Ui[m+4], di1);
        df0 = fmaf(hl[m], Uf[m], df0); df1 = fmaf(hl[m+4], Uf[m+4], df1);
        dg0 = fmaf(hl[m], Ug[m], dg0); dg1 = fmaf(hl[m+4], Ug[m+4], dg1);
        dq0 = fmaf(hl[m], Uo[m], dq0); dq1 = fmaf(hl[m+4], Uo[m+4], dq1);
    }
    const float zi = fmaf(di0 + di1, r2, z4.x);
    const float zf = fmaf(df0 + df1, r2, z4.y);
    const float zg = fmaf(dg0 + dg1, r2, z4.z);
    const float zo = fmaf(dq0 + dq1, r2, z4.w);

    const float iv = sigmoidf(zi);
    const float fv = sigmoidf(zf);
    const float ov = sigmoidf(zo);

    const float eg = real ? __expf(zg) : 0.0f;
    float s1 = eg;
    s1 += dppf<DPP_XOR1>(s1);
    s1 += dppf<DPP_XOR2>(s1);
    s1 += dpp_xor4(s1);
    c = fmaf(fv, c, (iv * eg) * fast_rcp(s1));

    const float ec = real ? __expf(c) : 0.0f;   // defer-max (uniform exp(-m) cancels)
    float s2 = ec;
    s2 += dppf<DPP_XOR1>(s2);
    s2 += dppf<DPP_XOR2>(s2);
    s2 += dpp_xor4(s2);

    const float ovec = ov * ec;
    hl[0] = ovec;
    hl[1] = dppf<DPP_XOR1>(ovec);
    hl[2] = dppf<DPP_XOR2>(ovec);
    hl[3] = dppf<DPP_XOR3>(ovec);
    const float h7 = dppf<DPP_HALF>(ovec);
    hl[7] = h7;
    hl[6] = dppf<DPP_XOR1>(h7);
    hl[5] = dppf<DPP_XOR2>(h7);
    hl[4] = dppf<DPP_XOR3>(h7);
    r2 = fast_rcp(s2);
    return ovec * r2;
}

// K2 (byte-identical to R17-R23, verified): deferred-y scan + parallel dense(10).
__global__ __launch_bounds__(64, 1) void k_scan(
    const float* __restrict__ xz, const float* __restrict__ Ul,
    const float* __restrict__ W10, const float* __restrict__ b10,
    const float* __restrict__ Wo, const float* __restrict__ bo,
    float* __restrict__ out)
{
    const int lane = threadIdx.x;
    const int j = lane & 7;
    const int grp = lane >> 3;
    const int b = blockIdx.x * 8 + grp;
    const bool real = (j < HH);

    __shared__ __align__(1024) float ring[16 * 256];   // 16 steps x 1KB
    __shared__ __align__(16) float h_lds[TT * 64];     // 64KB: h[t][lane]

    float Ui[8], Uf[8], Ug[8], Uo[8];
#pragma unroll
    for (int m = 0; m < 8; ++m) {
        const int src = j ^ m;
        const bool ok = real && (src < HH);
        const float* row = Ul + (ok ? src : 0) * 24;
        Ui[m] = ok ? row[0  + j] : 0.0f;
        Uf[m] = ok ? row[6  + j] : 0.0f;
        Ug[m] = ok ? row[12 + j] : 0.0f;
        Uo[m] = ok ? row[18 + j] : 0.0f;
    }

    float hl[8];
    float r2 = 1.0f, c = 0.0f;
#pragma unroll
    for (int m = 0; m < 8; ++m) hl[m] = 0.0f;

    const float* gsrc = xz + (size_t)b * (TT * 24) + j * 4;

#define STAGE(G) { \
        const float* s_ = gsrc + (size_t)((G) * 8) * 24; \
        float* lb_ = ring + (((G) * 8) & 15) * 256; \
        _Pragma("unroll") \
        for (int k_ = 0; k_ < 8; ++k_) gl_lds16(s_ + k_ * 24, lb_ + k_ * 256); }

    STAGE(0) STAGE(1)
    asm volatile("s_waitcnt vmcnt(8)" ::: "memory");   // group 0 resident

    float4 zcur = *(const float4*)(ring + 0 * 256 + lane * 4);
    float4 zn1  = *(const float4*)(ring + 1 * 256 + lane * 4);

#define STEP(K) { \
        const float4 zn2 = *(const float4*)(ring + (((sb + (K) + 2) & 15) << 8) + lane * 4); \
        const float hn = chain_step(hl, c, r2, Ui, Uf, Ug, Uo, zcur, real); \
        h_lds[((t0 + (K)) << 6) + lane] = hn; \
        zcur = zn1; zn1 = zn2; }

#pragma unroll 1
    for (int gi = 0; gi < 32; ++gi) {
        const int t0 = gi * 8;
        const int sb = (gi & 1) * 8;
        STEP(0) STEP(1) STEP(2) STEP(3) STEP(4) STEP(5)
        if (gi < 30) {
            STAGE(gi + 2)
            asm volatile("s_waitcnt vmcnt(8)" ::: "memory");
        } else if (gi == 30) {
            asm volatile("s_waitcnt vmcnt(0)" ::: "memory");   // group 31 resident
        }
        STEP(6) STEP(7)
    }
#undef STEP
#undef STAGE

    asm volatile("s_waitcnt lgkmcnt(0)" ::: "memory");
    __builtin_amdgcn_sched_barrier(0);

    // Phase 2: y[p] = sum over my t-slice {t = 8*tb + j} of sum_u h[t][u]*W10[t*6+u][p]
    float yl[10];
#pragma unroll
    for (int p = 0; p < 10; ++p) yl[p] = 0.0f;

#pragma unroll 2
    for (int tb = 0; tb < 32; ++tb) {
        const int t = tb * 8 + j;
        const float* hb = h_lds + (t << 6) + (grp << 3);
        const float2 h01 = *(const float2*)(hb + 0);
        const float2 h23 = *(const float2*)(hb + 2);
        const float2 h45 = *(const float2*)(hb + 4);
        const float* wr = W10 + (size_t)t * 60;
#define ACCU(U, HV) { \
        const float2 w0 = *(const float2*)(wr + (U) * 10 + 0); \
        const float2 w1 = *(const float2*)(wr + (U) * 10 + 2); \
        const float2 w2 = *(const float2*)(wr + (U) * 10 + 4); \
        const float2 w3 = *(const float2*)(wr + (U) * 10 + 6); \
        const float2 w4 = *(const float2*)(wr + (U) * 10 + 8); \
        yl[0] = fmaf(HV, w0.x, yl[0]); yl[1] = fmaf(HV, w0.y, yl[1]); \
        yl[2] = fmaf(HV, w1.x, yl[2]); yl[3] = fmaf(HV, w1.y, yl[3]); \
        yl[4] = fmaf(HV, w2.x, yl[4]); yl[5] = fmaf(HV, w2.y, yl[5]); \
        yl[6] = fmaf(HV, w3.x, yl[6]); yl[7] = fmaf(HV, w3.y, yl[7]); \
        yl[8] = fmaf(HV, w4.x, yl[8]); yl[9] = fmaf(HV, w4.y, yl[9]); }
        ACCU(0, h01.x) ACCU(1, h01.y) ACCU(2, h23.x)
        ACCU(3, h23.y) ACCU(4, h45.x) ACCU(5, h45.y)
#undef ACCU
    }

#pragma unroll
    for (int p = 0; p < 10; ++p) {
        float v = yl[p];
        v += dppf<DPP_XOR1>(v);
        v += dppf<DPP_XOR2>(v);
        v += dpp_xor4(v);
        yl[p] = v;
    }

    float o8 = bo[j];
#pragma unroll
    for (int p = 0; p < 10; ++p) o8 = fmaf(yl[p] + b10[p], Wo[p * 8 + j], o8);
    out[(size_t)b * 8 + j] = o8;
}

extern "C" void kernel_launch(void* const* d_in, const int* in_sizes, int n_in,
                              void* d_out, int out_size, void* d_ws, size_t ws_size,
                              hipStream_t stream) {
    const float* x   = (const float*)d_in[0];
    const float* Wa  = (const float*)d_in[1];
    const float* ba  = (const float*)d_in[2];
    const float* Wl  = (const float*)d_in[3];
    const float* Ul  = (const float*)d_in[4];
    const float* bl  = (const float*)d_in[5];
    const float* W10 = (const float*)d_in[6];
    const float* b10 = (const float*)d_in[7];
    const float* Wo  = (const float*)d_in[8];
    const float* bo  = (const float*)d_in[9];
    float* out = (float*)d_out;
    float* xz  = (float*)d_ws;   // BB*TT*24*4 = 96 MiB

    // waves = BB*TT / (16 items * 2 tiles * K1_DITERS) = 8192 -> 2048 blocks
    hipLaunchKernelGGL(k_attn_xz, dim3(BB * TT / (16 * 2 * K1_DITERS * 4)), dim3(256), 0, stream,
                       x, Wa, ba, Wl, bl, xz);
    hipLaunchKernelGGL(k_scan, dim3(BB / 8), dim3(64), 0, stream,
                       xz, Ul, W10, b10, Wo, bo, out);
}